// Round 1
// baseline (175.187 us; speedup 1.0000x reference)
//
#include <hip/hip_runtime.h>

// VQ-VAE vector quantizer, MI355X fp32 baseline.
// inputs:  [16][128][64][64] f32 (NCHW), codebook e: [512][128] f32
// output:  [16][128][64][64] f32 = e[argmin_k ||x-e_k||^2] scattered back.
// score = x.e - 0.5*||e||^2  (argmax score == argmin dist; ||x||^2 constant/token)

#define NB 16
#define ND 128
#define NHW 4096   // 64*64
#define NK 512
#define TILE_T 64  // tokens per block
#define KC 64      // codebook chunk

__global__ __launch_bounds__(128) void vq_enorm(const float* __restrict__ e,
                                                float* __restrict__ ens) {
  const int k = blockIdx.x;
  const int d = threadIdx.x;
  const float v = e[k * ND + d];
  float s = v * v;
  #pragma unroll
  for (int off = 32; off > 0; off >>= 1) s += __shfl_down(s, off, 64);
  __shared__ float tmp[2];
  if ((d & 63) == 0) tmp[d >> 6] = s;
  __syncthreads();
  if (d == 0) ens[k] = tmp[0] + tmp[1];
}

__global__ __launch_bounds__(256, 2) void vq_main(const float* __restrict__ x,
                                                  const float* __restrict__ e,
                                                  const float* __restrict__ ens,
                                                  float* __restrict__ out) {
  __shared__ float xs[ND][TILE_T];     // 32KB, [d][t] transposed tile
  __shared__ float es[ND][KC];         // 32KB, [d][k] transposed codebook chunk
  __shared__ float ensh[NK];           // 2KB
  __shared__ float red_v[TILE_T][17];  // padded (+1) vs 32-bank stride
  __shared__ int   red_i[TILE_T][17];
  __shared__ int   bidx[TILE_T];

  const int tid = threadIdx.x;
  const int b   = blockIdx.x >> 6;
  const int hw0 = (blockIdx.x & 63) * TILE_T;
  const float* xb = x + ((size_t)b * ND) * NHW;

  // stage X tile: coalesced float4 along hw, contiguous float4 LDS writes
  #pragma unroll
  for (int i = 0; i < 8; ++i) {
    const int f = tid + 256 * i;          // 2048 float4s
    const int d = f >> 4, t4 = f & 15;
    const float4 v = *(const float4*)(xb + (size_t)d * NHW + hw0 + 4 * t4);
    *(float4*)&xs[d][4 * t4] = v;
  }
  #pragma unroll
  for (int i = 0; i < 2; ++i) ensh[tid + 256 * i] = ens[tid + 256 * i];

  const int t4 = tid & 15;   // token group (4 tokens)
  const int m  = tid >> 4;   // k group within chunk (4 codes), 0..15

  float bv[4] = {-3.0e38f, -3.0e38f, -3.0e38f, -3.0e38f};
  int   bi[4] = {0, 0, 0, 0};

  for (int kc = 0; kc < NK / KC; ++kc) {
    __syncthreads();  // protect previous chunk's readers (and first xs stage)
    // stage codebook chunk transposed: lanes share d-quad, k contiguous in LDS
    #pragma unroll
    for (int i = 0; i < 8; ++i) {
      const int f = tid + 256 * i;       // 2048 float4s
      const int kk = f & 63, dq = f >> 6;
      const float4 v = *(const float4*)(e + (size_t)(kc * KC + kk) * ND + 4 * dq);
      es[4 * dq + 0][kk] = v.x;
      es[4 * dq + 1][kk] = v.y;
      es[4 * dq + 2][kk] = v.z;
      es[4 * dq + 3][kk] = v.w;
    }
    __syncthreads();

    float acc[4][4];
    #pragma unroll
    for (int a = 0; a < 4; ++a)
      #pragma unroll
      for (int c = 0; c < 4; ++c) acc[a][c] = 0.0f;

    #pragma unroll 8
    for (int d = 0; d < ND; ++d) {
      const float4 xv = *(const float4*)&xs[d][4 * t4];  // 4-way lane broadcast
      const float4 ev = *(const float4*)&es[d][4 * m];   // 16-way lane broadcast
      const float xa[4] = {xv.x, xv.y, xv.z, xv.w};
      const float ea[4] = {ev.x, ev.y, ev.z, ev.w};
      #pragma unroll
      for (int a = 0; a < 4; ++a)
        #pragma unroll
        for (int c = 0; c < 4; ++c)
          acc[a][c] = fmaf(xa[a], ea[c], acc[a][c]);
    }

    const int kbase = kc * KC + 4 * m;
    #pragma unroll
    for (int c = 0; c < 4; ++c) {
      const float bias = 0.5f * ensh[kbase + c];
      const int kg = kbase + c;
      #pragma unroll
      for (int a = 0; a < 4; ++a) {
        const float s = acc[a][c] - bias;
        if (s > bv[a] || (s == bv[a] && kg < bi[a])) { bv[a] = s; bi[a] = kg; }
      }
    }
  }

  // cross-thread argmax reduce: 16 partials per token
  #pragma unroll
  for (int a = 0; a < 4; ++a) {
    red_v[4 * t4 + a][m] = bv[a];
    red_i[4 * t4 + a][m] = bi[a];
  }
  __syncthreads();
  if (tid < TILE_T) {
    float v = red_v[tid][0]; int ix = red_i[tid][0];
    #pragma unroll
    for (int j = 1; j < 16; ++j) {
      const float vj = red_v[tid][j]; const int ij = red_i[tid][j];
      if (vj > v || (vj == v && ij < ix)) { v = vj; ix = ij; }
    }
    bidx[tid] = ix;
  }
  __syncthreads();

  // scatter codebook rows back to NCHW: coalesced 256B stores per d
  const int t = tid & 63, dg = tid >> 6;
  const float* er = e + (size_t)bidx[t] * ND;
  float* ob = out + ((size_t)b * ND) * NHW + hw0 + t;
  #pragma unroll
  for (int i = 0; i < 32; ++i) {
    const int d = dg * 32 + i;
    ob[(size_t)d * NHW] = er[d];
  }
}

extern "C" void kernel_launch(void* const* d_in, const int* in_sizes, int n_in,
                              void* d_out, int out_size, void* d_ws, size_t ws_size,
                              hipStream_t stream) {
  const float* x = (const float*)d_in[0];   // [16,128,64,64] f32
  const float* e = (const float*)d_in[1];   // [512,128] f32
  float* out = (float*)d_out;
  float* ens = (float*)d_ws;                // 512 floats scratch
  vq_enorm<<<NK, 128, 0, stream>>>(e, ens);
  vq_main<<<NB * (NHW / TILE_T), 256, 0, stream>>>(x, e, ens, out);
}

// Round 3
// 70.134 us; speedup vs baseline: 2.4979x; 2.4979x over previous
//
#include <hip/hip_runtime.h>

// VQ-VAE vector quantizer, MI355X — fp16-split (3-term) MFMA version.
// score(t,k) = x_t . e_k - 0.5*||e_k||^2  (argmax == argmin distance)
// x.e computed as  x_hi.e_hi + (x_hi.e_lo' + x_lo'.e_hi)/2048  with
// *_lo' = (v - fp16(v)) * 2048 cast to fp16 (keeps lo out of denormal range).

typedef _Float16 f16;
typedef _Float16 f16x4 __attribute__((ext_vector_type(4)));
typedef _Float16 f16x8 __attribute__((ext_vector_type(8)));
typedef float f32x16 __attribute__((ext_vector_type(16)));

#define ND 128
#define NK 512
#define NHW 4096
#define NTOK 65536
#define LO_SCALE 2048.0f
#define LO_INV (1.0f / 2048.0f)

// workspace layout (bytes)
#define WS_XHI 0
#define WS_XLO 16777216u
#define WS_EHI 33554432u
#define WS_ELO 33685504u
#define WS_ENS 33816576u
#define WS_NEED 33818624u

// ---------------------------------------------------------------- prep ------
// blocks 0..1023: transpose+split x (64 tokens each)
// blocks 1024..1055: split+swizzle e (16 rows each) + 0.5*||e||^2
__global__ __launch_bounds__(256) void vq_prep(const float* __restrict__ x,
                                               const float* __restrict__ e,
                                               f16* __restrict__ xhi, f16* __restrict__ xlo,
                                               f16* __restrict__ ehi, f16* __restrict__ elo,
                                               float* __restrict__ ens) {
  const int tid = threadIdx.x;
  if (blockIdx.x < 1024) {
    __shared__ float sc[ND][65];  // padded fp32 transpose scratch
    const int tok0 = blockIdx.x * 64;
    const int b = blockIdx.x >> 6;
    const int hw0 = (blockIdx.x & 63) * 64;
    const float* xb = x + (size_t)b * ND * NHW + hw0;
    #pragma unroll
    for (int it = 0; it < 8; ++it) {
      const int f = tid + 256 * it;
      const int d = f >> 4, t4 = (f & 15) * 4;
      const float4 v = *(const float4*)(xb + (size_t)d * NHW + t4);
      sc[d][t4 + 0] = v.x; sc[d][t4 + 1] = v.y;
      sc[d][t4 + 2] = v.z; sc[d][t4 + 3] = v.w;
    }
    __syncthreads();
    const int oct = tid & 15, trow = tid >> 4;
    #pragma unroll
    for (int p = 0; p < 4; ++p) {
      const int t = p * 16 + trow;
      float v[8];
      #pragma unroll
      for (int j = 0; j < 8; ++j) v[j] = sc[oct * 8 + j][t];
      f16x8 h, l;
      #pragma unroll
      for (int j = 0; j < 8; ++j) {
        const f16 hv = (f16)v[j];
        h[j] = hv;
        l[j] = (f16)((v[j] - (float)hv) * LO_SCALE);
      }
      const size_t off = (size_t)(tok0 + t) * ND + oct * 8;
      *(f16x8*)(xhi + off) = h;
      *(f16x8*)(xlo + off) = l;
    }
  } else {
    const int k0 = ((int)blockIdx.x - 1024) * 16;
    const int r = tid >> 4, dq16 = tid & 15;
    const int k = k0 + r;
    float ssum = 0.0f;
    #pragma unroll
    for (int hh = 0; hh < 2; ++hh) {
      const int dq = dq16 + 16 * hh;
      const float4 v = *(const float4*)(e + (size_t)k * ND + 4 * dq);
      ssum += v.x * v.x + v.y * v.y + v.z * v.z + v.w * v.w;
      float va[4] = {v.x, v.y, v.z, v.w};
      f16x4 hv, lv;
      #pragma unroll
      for (int j = 0; j < 4; ++j) {
        const f16 h = (f16)va[j];
        hv[j] = h;
        lv[j] = (f16)((va[j] - (float)h) * LO_SCALE);
      }
      const int slot = dq >> 1;
      const int sl = slot ^ (k & 15);                 // XOR swizzle, 16B slots
      const size_t off = (size_t)k * ND + sl * 8 + (dq & 1) * 4;
      *(f16x4*)(ehi + off) = hv;
      *(f16x4*)(elo + off) = lv;
    }
    #pragma unroll
    for (int m = 1; m < 16; m <<= 1) ssum += __shfl_xor(ssum, m, 64);
    if (dq16 == 0) ens[k] = 0.5f * ssum;
  }
}

// ---------------------------------------------------------------- main ------
// 256 blocks x 512 threads (8 waves). Wave w: tokens blk*256 + 32w .. +32.
// A (x hi/lo frags) in registers; e chunks (128 codes) double-buffered in LDS.
__global__ __launch_bounds__(512, 2) void vq_mfma(const f16* __restrict__ xhi,
                                                  const f16* __restrict__ xlo,
                                                  const f16* __restrict__ ehi,
                                                  const f16* __restrict__ elo,
                                                  const float* __restrict__ ens,
                                                  const float* __restrict__ e32,
                                                  float* __restrict__ out) {
  __shared__ f16 es[2][2][128 * 128];  // [buf][hi/lo][row*128 + swizzled d]
  __shared__ float ens_s[NK];
  __shared__ int bidx_s[256];

  const int tid = threadIdx.x;
  const int w = tid >> 6;
  const int lane = tid & 63;
  const int row32 = lane & 31;
  const int half = lane >> 5;

  const int T0 = blockIdx.x * 256;
  const int tok = T0 + w * 32 + row32;

  ens_s[tid] = ens[tid];  // NK == blockDim

  // stage chunk 0 into regs
  uint4 sreg[4][2];
  #pragma unroll
  for (int p = 0; p < 4; ++p) {
    const size_t so = (size_t)p * 4096 + tid * 8;
    sreg[p][0] = *(const uint4*)(ehi + so);
    sreg[p][1] = *(const uint4*)(elo + so);
  }
  // A fragments: 8 k-steps x (hi,lo)
  f16x8 Ah[8], Al[8];
  #pragma unroll
  for (int ks = 0; ks < 8; ++ks) {
    const size_t off = (size_t)tok * ND + ks * 16 + half * 8;
    Ah[ks] = *(const f16x8*)(xhi + off);
    Al[ks] = *(const f16x8*)(xlo + off);
  }
  #pragma unroll
  for (int p = 0; p < 4; ++p) {
    *(uint4*)&es[0][0][p * 4096 + tid * 8] = sreg[p][0];
    *(uint4*)&es[0][1][p * 4096 + tid * 8] = sreg[p][1];
  }
  __syncthreads();

  float bv[16];
  int bi[16];
  #pragma unroll
  for (int r = 0; r < 16; ++r) { bv[r] = -3.0e38f; bi[r] = 0; }

  int cur = 0;
  for (int c = 0; c < 4; ++c) {
    if (c < 3) {  // prefetch next chunk global->regs (latency hides under MFMA)
      const size_t src0 = (size_t)(c + 1) * 16384;
      #pragma unroll
      for (int p = 0; p < 4; ++p) {
        const size_t so = src0 + p * 4096 + tid * 8;
        sreg[p][0] = *(const uint4*)(ehi + so);
        sreg[p][1] = *(const uint4*)(elo + so);
      }
    }
    const int kb = c * 128;
    for (int ni = 0; ni < 4; ++ni) {
      const int cr = ni * 32 + row32;   // code row within chunk
      const int code = kb + cr;
      f32x16 acc1 = {}, acc2 = {}, acc3 = {};
      #pragma unroll
      for (int ks = 0; ks < 8; ++ks) {
        const int sl = ((2 * ks + half) ^ (cr & 15)) * 8;
        const f16x8 bh = *(const f16x8*)&es[cur][0][cr * 128 + sl];
        const f16x8 bl = *(const f16x8*)&es[cur][1][cr * 128 + sl];
        acc1 = __builtin_amdgcn_mfma_f32_32x32x16_f16(Ah[ks], bh, acc1, 0, 0, 0);
        acc2 = __builtin_amdgcn_mfma_f32_32x32x16_f16(Ah[ks], bl, acc2, 0, 0, 0);
        acc3 = __builtin_amdgcn_mfma_f32_32x32x16_f16(Al[ks], bh, acc3, 0, 0, 0);
      }
      const float bias = ens_s[code];
      #pragma unroll
      for (int r = 0; r < 16; ++r) {
        const float s = acc1[r] + (acc2[r] + acc3[r]) * LO_INV - bias;
        if (s > bv[r]) { bv[r] = s; bi[r] = code; }  // strict > keeps lower idx
      }
    }
    __syncthreads();  // everyone done reading es[cur]
    if (c < 3) {
      #pragma unroll
      for (int p = 0; p < 4; ++p) {
        *(uint4*)&es[cur ^ 1][0][p * 4096 + tid * 8] = sreg[p][0];
        *(uint4*)&es[cur ^ 1][1][p * 4096 + tid * 8] = sreg[p][1];
      }
    }
    __syncthreads();  // staged writes visible
    cur ^= 1;
  }

  // argmax reduce across the 32 lanes sharing a row-set (cols of C)
  #pragma unroll
  for (int r = 0; r < 16; ++r) {
    #pragma unroll
    for (int m = 1; m < 32; m <<= 1) {
      const float ov = __shfl_xor(bv[r], m, 64);
      const int oi = __shfl_xor(bi[r], m, 64);
      if (ov > bv[r] || (ov == bv[r] && oi < bi[r])) { bv[r] = ov; bi[r] = oi; }
    }
    const int rowr = (r & 3) + 8 * (r >> 2) + 4 * half;  // C/D row mapping (m74)
    if (row32 == r) bidx_s[w * 32 + rowr] = bi[r];
  }
  __syncthreads();

  // scatter codebook rows back to NCHW (coalesced along hw)
  const int tloc = tid & 255;
  const int dg = tid >> 8;
  const int Tg = T0 + tloc;
  const int bb = Tg >> 12;
  const int hw = Tg & 4095;
  const float* er = e32 + (size_t)bidx_s[tloc] * ND;
  float* ob = out + (size_t)bb * ND * NHW + hw;
  #pragma unroll
  for (int j4 = 0; j4 < 16; ++j4) {
    const int d = dg * 64 + j4 * 4;
    const float4 ev = *(const float4*)(er + d);
    ob[(size_t)(d + 0) * NHW] = ev.x;
    ob[(size_t)(d + 1) * NHW] = ev.y;
    ob[(size_t)(d + 2) * NHW] = ev.z;
    ob[(size_t)(d + 3) * NHW] = ev.w;
  }
}

// ------------------------------------------------- fallback (round-1 fp32) --
__global__ __launch_bounds__(128) void vq_enorm(const float* __restrict__ e,
                                                float* __restrict__ ensw) {
  const int k = blockIdx.x;
  const int d = threadIdx.x;
  const float v = e[k * ND + d];
  float s = v * v;
  #pragma unroll
  for (int off = 32; off > 0; off >>= 1) s += __shfl_down(s, off, 64);
  __shared__ float tmp[2];
  if ((d & 63) == 0) tmp[d >> 6] = s;
  __syncthreads();
  if (d == 0) ensw[k] = tmp[0] + tmp[1];
}

__global__ __launch_bounds__(256, 2) void vq_main_f32(const float* __restrict__ x,
                                                      const float* __restrict__ e,
                                                      const float* __restrict__ ensw,
                                                      float* __restrict__ out) {
  __shared__ float xs[ND][64];
  __shared__ float esh[ND][64];
  __shared__ float enh[NK];
  __shared__ float red_v[64][17];
  __shared__ int red_i[64][17];
  __shared__ int bidx[64];
  const int tid = threadIdx.x;
  const int b = blockIdx.x >> 6;
  const int hw0 = (blockIdx.x & 63) * 64;
  const float* xb = x + ((size_t)b * ND) * NHW;
  #pragma unroll
  for (int i = 0; i < 8; ++i) {
    const int f = tid + 256 * i;
    const int d = f >> 4, t4 = f & 15;
    const float4 v = *(const float4*)(xb + (size_t)d * NHW + hw0 + 4 * t4);
    *(float4*)&xs[d][4 * t4] = v;
  }
  #pragma unroll
  for (int i = 0; i < 2; ++i) enh[tid + 256 * i] = ensw[tid + 256 * i];
  const int t4 = tid & 15, m = tid >> 4;
  float bvv[4] = {-3.0e38f, -3.0e38f, -3.0e38f, -3.0e38f};
  int bii[4] = {0, 0, 0, 0};
  for (int kc = 0; kc < NK / 64; ++kc) {
    __syncthreads();
    #pragma unroll
    for (int i = 0; i < 8; ++i) {
      const int f = tid + 256 * i;
      const int kk = f & 63, dq = f >> 6;
      const float4 v = *(const float4*)(e + (size_t)(kc * 64 + kk) * ND + 4 * dq);
      esh[4 * dq + 0][kk] = v.x; esh[4 * dq + 1][kk] = v.y;
      esh[4 * dq + 2][kk] = v.z; esh[4 * dq + 3][kk] = v.w;
    }
    __syncthreads();
    float acc[4][4];
    #pragma unroll
    for (int a = 0; a < 4; ++a)
      #pragma unroll
      for (int cc = 0; cc < 4; ++cc) acc[a][cc] = 0.0f;
    #pragma unroll 8
    for (int d = 0; d < ND; ++d) {
      const float4 xv = *(const float4*)&xs[d][4 * t4];
      const float4 ev = *(const float4*)&esh[d][4 * m];
      const float xa[4] = {xv.x, xv.y, xv.z, xv.w};
      const float ea[4] = {ev.x, ev.y, ev.z, ev.w};
      #pragma unroll
      for (int a = 0; a < 4; ++a)
        #pragma unroll
        for (int cc = 0; cc < 4; ++cc) acc[a][cc] = fmaf(xa[a], ea[cc], acc[a][cc]);
    }
    const int kbase = kc * 64 + 4 * m;
    #pragma unroll
    for (int cc = 0; cc < 4; ++cc) {
      const float bias = 0.5f * enh[kbase + cc];
      const int kg = kbase + cc;
      #pragma unroll
      for (int a = 0; a < 4; ++a) {
        const float s = acc[a][cc] - bias;
        if (s > bvv[a] || (s == bvv[a] && kg < bii[a])) { bvv[a] = s; bii[a] = kg; }
      }
    }
  }
  #pragma unroll
  for (int a = 0; a < 4; ++a) { red_v[4 * t4 + a][m] = bvv[a]; red_i[4 * t4 + a][m] = bii[a]; }
  __syncthreads();
  if (tid < 64) {
    float v = red_v[tid][0]; int ix = red_i[tid][0];
    #pragma unroll
    for (int j = 1; j < 16; ++j) {
      const float vj = red_v[tid][j]; const int ij = red_i[tid][j];
      if (vj > v || (vj == v && ij < ix)) { v = vj; ix = ij; }
    }
    bidx[tid] = ix;
  }
  __syncthreads();
  const int t = tid & 63, dgg = tid >> 6;
  const float* er = e + (size_t)bidx[t] * ND;
  float* ob = out + ((size_t)b * ND) * NHW + hw0 + t;
  #pragma unroll
  for (int i = 0; i < 32; ++i) ob[(size_t)(dgg * 32 + i) * NHW] = er[dgg * 32 + i];
}

// --------------------------------------------------------------- launch -----
extern "C" void kernel_launch(void* const* d_in, const int* in_sizes, int n_in,
                              void* d_out, int out_size, void* d_ws, size_t ws_size,
                              hipStream_t stream) {
  const float* x = (const float*)d_in[0];
  const float* e = (const float*)d_in[1];
  float* out = (float*)d_out;
  char* ws = (char*)d_ws;

  if (ws_size >= WS_NEED) {
    f16* xhi = (f16*)(ws + WS_XHI);
    f16* xlo = (f16*)(ws + WS_XLO);
    f16* ehi = (f16*)(ws + WS_EHI);
    f16* elo = (f16*)(ws + WS_ELO);
    float* ens = (float*)(ws + WS_ENS);
    vq_prep<<<1056, 256, 0, stream>>>(x, e, xhi, xlo, ehi, elo, ens);
    vq_mfma<<<256, 512, 0, stream>>>(xhi, xlo, ehi, elo, ens, e, out);
  } else {
    float* ens = (float*)d_ws;
    vq_enorm<<<NK, 128, 0, stream>>>(e, ens);
    vq_main_f32<<<16 * 64, 256, 0, stream>>>(x, e, ens, out);
  }
}

// Round 6
// 68.743 us; speedup vs baseline: 2.5484x; 1.0202x over previous
//
#include <hip/hip_runtime.h>

// VQ-VAE vector quantizer, MI355X — v4: code-in-reg / token-in-LDS MFMA,
// single-barrier score kernel + atomic argmax merge + separate scatter.
// score(t,k) = x_t . e_k - 0.5*||e_k||^2  (argmax == argmin distance)
// x.e = xh.eh + (xh.el' + xl'.eh)/2048, *_lo' = (v - fp16(v))*2048 as fp16.

typedef _Float16 f16;
typedef _Float16 f16x4 __attribute__((ext_vector_type(4)));
typedef _Float16 f16x8 __attribute__((ext_vector_type(8)));
typedef float f32x16 __attribute__((ext_vector_type(16)));

#define ND 128
#define NK 512
#define NHW 4096
#define NTOK 65536
#define LO_SCALE 2048.0f
#define LO_INV (1.0f / 2048.0f)

// workspace layout (bytes)
#define WS_XHI 0
#define WS_XLO 16777216u
#define WS_EHI 33554432u
#define WS_ELO 33685504u
#define WS_ENS 33816576u
#define WS_NEED_V3 33818624u            // round-3 (middle tier) footprint
#define WS_WIN 33818624u
#define WS_NEED_V4 34342912u            // v4 footprint (+512KB winners)

__device__ __forceinline__ unsigned mono_key(float v) {
  const unsigned u = __float_as_uint(v);
  return (u & 0x80000000u) ? ~u : (u | 0x80000000u);
}

// ================================================================ v4 ========
// prep3: blocks 0..1023 transpose+split x (SWIZZLED slots);
//        blocks 1024..1055 split e PLAIN + 0.5*||e||^2;
//        blocks 1056..1311 zero the winners array.
__global__ __launch_bounds__(256) void vq_prep3(const float* __restrict__ x,
                                                const float* __restrict__ e,
                                                f16* __restrict__ xhi, f16* __restrict__ xlo,
                                                f16* __restrict__ ehi, f16* __restrict__ elo,
                                                float* __restrict__ ens,
                                                unsigned long long* __restrict__ win) {
  const int tid = threadIdx.x;
  if (blockIdx.x < 1024) {
    __shared__ float sc[ND][65];  // padded fp32 transpose scratch
    const int tok0 = blockIdx.x * 64;
    const int b = blockIdx.x >> 6;
    const int hw0 = (blockIdx.x & 63) * 64;
    const float* xb = x + (size_t)b * ND * NHW + hw0;
    #pragma unroll
    for (int it = 0; it < 8; ++it) {
      const int f = tid + 256 * it;
      const int d = f >> 4, t4 = (f & 15) * 4;
      const float4 v = *(const float4*)(xb + (size_t)d * NHW + t4);
      sc[d][t4 + 0] = v.x; sc[d][t4 + 1] = v.y;
      sc[d][t4 + 2] = v.z; sc[d][t4 + 3] = v.w;
    }
    __syncthreads();
    const int oct = tid & 15, trow = tid >> 4;
    #pragma unroll
    for (int p = 0; p < 4; ++p) {
      const int t = p * 16 + trow;
      const int tok = tok0 + t;
      float v[8];
      #pragma unroll
      for (int j = 0; j < 8; ++j) v[j] = sc[oct * 8 + j][t];
      f16x8 h, l;
      #pragma unroll
      for (int j = 0; j < 8; ++j) {
        const f16 hv = (f16)v[j];
        h[j] = hv;
        l[j] = (f16)((v[j] - (float)hv) * LO_SCALE);
      }
      const size_t off = (size_t)tok * ND + (size_t)((oct ^ (tok & 15)) * 8);
      *(f16x8*)(xhi + off) = h;
      *(f16x8*)(xlo + off) = l;
    }
  } else if (blockIdx.x < 1056) {
    const int k0 = ((int)blockIdx.x - 1024) * 16;
    const int r = tid >> 4, dq16 = tid & 15;
    const int k = k0 + r;
    float ssum = 0.0f;
    #pragma unroll
    for (int hh = 0; hh < 2; ++hh) {
      const int dq = dq16 + 16 * hh;
      const float4 v = *(const float4*)(e + (size_t)k * ND + 4 * dq);
      ssum += v.x * v.x + v.y * v.y + v.z * v.z + v.w * v.w;
      float va[4] = {v.x, v.y, v.z, v.w};
      f16x4 hv, lv;
      #pragma unroll
      for (int j = 0; j < 4; ++j) {
        const f16 h = (f16)va[j];
        hv[j] = h;
        lv[j] = (f16)((va[j] - (float)h) * LO_SCALE);
      }
      const size_t off = (size_t)k * ND + 4 * dq;   // PLAIN layout
      *(f16x4*)(ehi + off) = hv;
      *(f16x4*)(elo + off) = lv;
    }
    #pragma unroll
    for (int m = 1; m < 16; m <<= 1) ssum += __shfl_xor(ssum, m, 64);
    if (dq16 == 0) ens[k] = 0.5f * ssum;
  } else {
    win[((int)blockIdx.x - 1056) * 256 + tid] = 0ull;
  }
}

// score: grid 1024 = 512 token-tiles(128) x 2 code-chunks(256).
// 8 waves; wave w owns codes c*256 + w*32 .. +32 (A-frags in regs);
// x-tile hi/lo in LDS (B), loaded once; ONE main barrier.
__global__ __launch_bounds__(512) void vq_score(const f16* __restrict__ xhi,
                                                const f16* __restrict__ xlo,
                                                const f16* __restrict__ ehi,
                                                const f16* __restrict__ elo,
                                                const float* __restrict__ ens,
                                                unsigned long long* __restrict__ win) {
  __shared__ f16 xsh[128 * 128];           // 32KB x-hi tile (swizzled slots)
  __shared__ f16 xsl[128 * 128];           // 32KB x-lo tile
  __shared__ unsigned long long cand[128][9];  // per-token per-wave keys (+pad)

  const int tid = threadIdx.x;
  const int w = tid >> 6;
  const int lane = tid & 63;
  const int l31 = lane & 31;
  const int half = lane >> 5;
  const int tile = (int)blockIdx.x >> 1;
  const int c = (int)blockIdx.x & 1;
  const int T0 = tile * 128;
  const int cb = c * 256 + w * 32;         // wave's code base

  // stage x tile: global (pre-swizzled) -> regs -> LDS, linear
  uint4 r0[4], r1[4];
  {
    const f16* sh = xhi + (size_t)T0 * ND;
    const f16* sl = xlo + (size_t)T0 * ND;
    #pragma unroll
    for (int p = 0; p < 4; ++p) {
      r0[p] = *(const uint4*)(sh + p * 4096 + tid * 8);
      r1[p] = *(const uint4*)(sl + p * 4096 + tid * 8);
    }
  }

  // A fragments: this lane's code row (e hi/lo, plain layout), 8 k-steps
  const int acode = cb + l31;
  f16x8 Ah[8], Al[8];
  #pragma unroll
  for (int ks = 0; ks < 8; ++ks) {
    const size_t off = (size_t)acode * ND + ks * 16 + half * 8;
    Ah[ks] = *(const f16x8*)(ehi + off);
    Al[ks] = *(const f16x8*)(elo + off);
  }
  // bias per C/D row r: code cb + rowr(r,half)  (uniform across lanes in half)
  float biasv[16];
  #pragma unroll
  for (int r = 0; r < 16; ++r) {
    const int rowr = (r & 3) + 8 * (r >> 2) + 4 * half;
    biasv[r] = ens[cb + rowr];
  }

  #pragma unroll
  for (int p = 0; p < 4; ++p) {
    *(uint4*)&xsh[p * 4096 + tid * 8] = r0[p];
    *(uint4*)&xsl[p * 4096 + tid * 8] = r1[p];
  }
  __syncthreads();

  unsigned long long best[4];
  #pragma unroll
  for (int ni = 0; ni < 4; ++ni) {
    const int tt = ni * 32 + l31;          // this lane's token column
    f32x16 acc1 = {}, acc2 = {};
    #pragma unroll
    for (int ks = 0; ks < 8; ++ks) {
      const int sl = ((2 * ks + half) ^ (tt & 15)) * 8;
      const f16x8 bh = *(const f16x8*)&xsh[tt * 128 + sl];
      const f16x8 bl = *(const f16x8*)&xsl[tt * 128 + sl];
      acc2 = __builtin_amdgcn_mfma_f32_32x32x16_f16(Al[ks], bh, acc2, 0, 0, 0);
      acc1 = __builtin_amdgcn_mfma_f32_32x32x16_f16(Ah[ks], bh, acc1, 0, 0, 0);
      acc2 = __builtin_amdgcn_mfma_f32_32x32x16_f16(Ah[ks], bl, acc2, 0, 0, 0);
    }
    // lane-local argmax over the 16 code-rows
    float bv = -3.0e38f; int bi = 0;
    #pragma unroll
    for (int r = 0; r < 16; ++r) {
      const float s = acc1[r] + acc2[r] * LO_INV - biasv[r];
      const int cd = cb + (r & 3) + 8 * (r >> 2) + 4 * half;
      if (s > bv || (s == bv && cd < bi)) { bv = s; bi = cd; }
    }
    // merge across halves (token identical for lane ^ 32)
    const float ov = __shfl_xor(bv, 32, 64);
    const int oi = __shfl_xor(bi, 32, 64);
    if (ov > bv || (ov == bv && oi < bi)) { bv = ov; bi = oi; }
    best[ni] = ((unsigned long long)mono_key(bv) << 32) | (unsigned)(511 - bi);
  }

  #pragma unroll
  for (int ni = 0; ni < 4; ++ni)
    if (half == 0) cand[ni * 32 + l31][w] = best[ni];
  __syncthreads();
  if (tid < 128) {
    unsigned long long k = cand[tid][0];
    #pragma unroll
    for (int j = 1; j < 8; ++j) {
      const unsigned long long kj = cand[tid][j];
      k = (kj > k) ? kj : k;
    }
    atomicMax(win + T0 + tid, k);
  }
}

// scatter: 512 blocks x 512 thr; block = 128 tokens x 4 d-groups of 32
__global__ __launch_bounds__(512) void vq_scatter(const unsigned long long* __restrict__ win,
                                                  const float* __restrict__ e32,
                                                  float* __restrict__ out) {
  __shared__ int bidx_s[128];
  const int tid = threadIdx.x;
  const int T0 = (int)blockIdx.x * 128;
  if (tid < 128) bidx_s[tid] = 511 - (int)(win[T0 + tid] & 0x1FFull);
  __syncthreads();
  const int tloc = tid & 127, dg = tid >> 7;
  const int Tg = T0 + tloc;
  const int bb = Tg >> 12;
  const int hw = Tg & 4095;
  const float* er = e32 + (size_t)bidx_s[tloc] * ND;
  float* ob = out + (size_t)bb * ND * NHW + hw;
  #pragma unroll
  for (int j4 = 0; j4 < 8; ++j4) {
    const int d = dg * 32 + j4 * 4;
    const float4 ev = *(const float4*)(er + d);
    ob[(size_t)(d + 0) * NHW] = ev.x;
    ob[(size_t)(d + 1) * NHW] = ev.y;
    ob[(size_t)(d + 2) * NHW] = ev.z;
    ob[(size_t)(d + 3) * NHW] = ev.w;
  }
}

// ====================================================== v3 middle tier ======
__global__ __launch_bounds__(256) void vq_prep2(const float* __restrict__ x,
                                                const float* __restrict__ e,
                                                f16* __restrict__ xhi, f16* __restrict__ xlo,
                                                f16* __restrict__ ehi, f16* __restrict__ elo,
                                                float* __restrict__ ens) {
  const int tid = threadIdx.x;
  if (blockIdx.x < 1024) {
    __shared__ float sc[ND][65];
    const int tok0 = blockIdx.x * 64;
    const int b = blockIdx.x >> 6;
    const int hw0 = (blockIdx.x & 63) * 64;
    const float* xb = x + (size_t)b * ND * NHW + hw0;
    #pragma unroll
    for (int it = 0; it < 8; ++it) {
      const int f = tid + 256 * it;
      const int d = f >> 4, t4 = (f & 15) * 4;
      const float4 v = *(const float4*)(xb + (size_t)d * NHW + t4);
      sc[d][t4 + 0] = v.x; sc[d][t4 + 1] = v.y;
      sc[d][t4 + 2] = v.z; sc[d][t4 + 3] = v.w;
    }
    __syncthreads();
    const int oct = tid & 15, trow = tid >> 4;
    #pragma unroll
    for (int p = 0; p < 4; ++p) {
      const int t = p * 16 + trow;
      float v[8];
      #pragma unroll
      for (int j = 0; j < 8; ++j) v[j] = sc[oct * 8 + j][t];
      f16x8 h, l;
      #pragma unroll
      for (int j = 0; j < 8; ++j) {
        const f16 hv = (f16)v[j];
        h[j] = hv;
        l[j] = (f16)((v[j] - (float)hv) * LO_SCALE);
      }
      const size_t off = (size_t)(tok0 + t) * ND + oct * 8;  // plain x
      *(f16x8*)(xhi + off) = h;
      *(f16x8*)(xlo + off) = l;
    }
  } else {
    const int k0 = ((int)blockIdx.x - 1024) * 16;
    const int r = tid >> 4, dq16 = tid & 15;
    const int k = k0 + r;
    float ssum = 0.0f;
    #pragma unroll
    for (int hh = 0; hh < 2; ++hh) {
      const int dq = dq16 + 16 * hh;
      const float4 v = *(const float4*)(e + (size_t)k * ND + 4 * dq);
      ssum += v.x * v.x + v.y * v.y + v.z * v.z + v.w * v.w;
      float va[4] = {v.x, v.y, v.z, v.w};
      f16x4 hv, lv;
      #pragma unroll
      for (int j = 0; j < 4; ++j) {
        const f16 h = (f16)va[j];
        hv[j] = h;
        lv[j] = (f16)((va[j] - (float)h) * LO_SCALE);
      }
      const int sl = (dq >> 1) ^ (k & 15);               // swizzled e
      const size_t off = (size_t)k * ND + sl * 8 + (dq & 1) * 4;
      *(f16x4*)(ehi + off) = hv;
      *(f16x4*)(elo + off) = lv;
    }
    #pragma unroll
    for (int m = 1; m < 16; m <<= 1) ssum += __shfl_xor(ssum, m, 64);
    if (dq16 == 0) ens[k] = 0.5f * ssum;
  }
}

__global__ __launch_bounds__(512, 2) void vq_mfma(const f16* __restrict__ xhi,
                                                  const f16* __restrict__ xlo,
                                                  const f16* __restrict__ ehi,
                                                  const f16* __restrict__ elo,
                                                  const float* __restrict__ ens,
                                                  const float* __restrict__ e32,
                                                  float* __restrict__ out) {
  __shared__ f16 es[2][2][128 * 128];
  __shared__ float ens_s[NK];
  __shared__ int bidx_s[256];
  const int tid = threadIdx.x;
  const int w = tid >> 6;
  const int lane = tid & 63;
  const int row32 = lane & 31;
  const int half = lane >> 5;
  const int T0 = blockIdx.x * 256;
  const int tok = T0 + w * 32 + row32;
  ens_s[tid] = ens[tid];
  uint4 sreg[4][2];
  #pragma unroll
  for (int p = 0; p < 4; ++p) {
    const size_t so = (size_t)p * 4096 + tid * 8;
    sreg[p][0] = *(const uint4*)(ehi + so);
    sreg[p][1] = *(const uint4*)(elo + so);
  }
  f16x8 Ah[8], Al[8];
  #pragma unroll
  for (int ks = 0; ks < 8; ++ks) {
    const size_t off = (size_t)tok * ND + ks * 16 + half * 8;
    Ah[ks] = *(const f16x8*)(xhi + off);
    Al[ks] = *(const f16x8*)(xlo + off);
  }
  #pragma unroll
  for (int p = 0; p < 4; ++p) {
    *(uint4*)&es[0][0][p * 4096 + tid * 8] = sreg[p][0];
    *(uint4*)&es[0][1][p * 4096 + tid * 8] = sreg[p][1];
  }
  __syncthreads();
  float bv[16]; int bi[16];
  #pragma unroll
  for (int r = 0; r < 16; ++r) { bv[r] = -3.0e38f; bi[r] = 0; }
  int cur = 0;
  for (int c = 0; c < 4; ++c) {
    if (c < 3) {
      const size_t src0 = (size_t)(c + 1) * 16384;
      #pragma unroll
      for (int p = 0; p < 4; ++p) {
        const size_t so = src0 + p * 4096 + tid * 8;
        sreg[p][0] = *(const uint4*)(ehi + so);
        sreg[p][1] = *(const uint4*)(elo + so);
      }
    }
    const int kb = c * 128;
    for (int ni = 0; ni < 4; ++ni) {
      const int cr = ni * 32 + row32;
      const int code = kb + cr;
      f32x16 acc1 = {}, acc2 = {}, acc3 = {};
      #pragma unroll
      for (int ks = 0; ks < 8; ++ks) {
        const int sl = ((2 * ks + half) ^ (cr & 15)) * 8;
        const f16x8 bh = *(const f16x8*)&es[cur][0][cr * 128 + sl];
        const f16x8 bl = *(const f16x8*)&es[cur][1][cr * 128 + sl];
        acc1 = __builtin_amdgcn_mfma_f32_32x32x16_f16(Ah[ks], bh, acc1, 0, 0, 0);
        acc2 = __builtin_amdgcn_mfma_f32_32x32x16_f16(Ah[ks], bl, acc2, 0, 0, 0);
        acc3 = __builtin_amdgcn_mfma_f32_32x32x16_f16(Al[ks], bh, acc3, 0, 0, 0);
      }
      const float bias = ens_s[code];
      #pragma unroll
      for (int r = 0; r < 16; ++r) {
        const float s = acc1[r] + (acc2[r] + acc3[r]) * LO_INV - bias;
        if (s > bv[r]) { bv[r] = s; bi[r] = code; }
      }
    }
    __syncthreads();
    if (c < 3) {
      #pragma unroll
      for (int p = 0; p < 4; ++p) {
        *(uint4*)&es[cur ^ 1][0][p * 4096 + tid * 8] = sreg[p][0];
        *(uint4*)&es[cur ^ 1][1][p * 4096 + tid * 8] = sreg[p][1];
      }
    }
    __syncthreads();
    cur ^= 1;
  }
  #pragma unroll
  for (int r = 0; r < 16; ++r) {
    #pragma unroll
    for (int m = 1; m < 32; m <<= 1) {
      const float ov = __shfl_xor(bv[r], m, 64);
      const int oi = __shfl_xor(bi[r], m, 64);
      if (ov > bv[r] || (ov == bv[r] && oi < bi[r])) { bv[r] = ov; bi[r] = oi; }
    }
    const int rowr = (r & 3) + 8 * (r >> 2) + 4 * half;
    if (row32 == r) bidx_s[w * 32 + rowr] = bi[r];
  }
  __syncthreads();
  const int tloc = tid & 255;
  const int dg = tid >> 8;
  const int Tg = T0 + tloc;
  const int bb = Tg >> 12;
  const int hw = Tg & 4095;
  const float* er = e32 + (size_t)bidx_s[tloc] * ND;
  float* ob = out + (size_t)bb * ND * NHW + hw;
  #pragma unroll
  for (int j4 = 0; j4 < 16; ++j4) {
    const int d = dg * 64 + j4 * 4;
    const float4 ev = *(const float4*)(er + d);
    ob[(size_t)(d + 0) * NHW] = ev.x;
    ob[(size_t)(d + 1) * NHW] = ev.y;
    ob[(size_t)(d + 2) * NHW] = ev.z;
    ob[(size_t)(d + 3) * NHW] = ev.w;
  }
}

// ======================================================== fp32 last tier ====
__global__ __launch_bounds__(128) void vq_enorm(const float* __restrict__ e,
                                                float* __restrict__ ensw) {
  const int k = blockIdx.x;
  const int d = threadIdx.x;
  const float v = e[k * ND + d];
  float s = v * v;
  #pragma unroll
  for (int off = 32; off > 0; off >>= 1) s += __shfl_down(s, off, 64);
  __shared__ float tmp[2];
  if ((d & 63) == 0) tmp[d >> 6] = s;
  __syncthreads();
  if (d == 0) ensw[k] = tmp[0] + tmp[1];
}

__global__ __launch_bounds__(256, 2) void vq_main_f32(const float* __restrict__ x,
                                                      const float* __restrict__ e,
                                                      const float* __restrict__ ensw,
                                                      float* __restrict__ out) {
  __shared__ float xs[ND][64];
  __shared__ float esh[ND][64];
  __shared__ float enh[NK];
  __shared__ float red_v[64][17];
  __shared__ int red_i[64][17];
  __shared__ int bidx[64];
  const int tid = threadIdx.x;
  const int b = blockIdx.x >> 6;
  const int hw0 = (blockIdx.x & 63) * 64;
  const float* xb = x + ((size_t)b * ND) * NHW;
  #pragma unroll
  for (int i = 0; i < 8; ++i) {
    const int f = tid + 256 * i;
    const int d = f >> 4, t4 = f & 15;
    const float4 v = *(const float4*)(xb + (size_t)d * NHW + hw0 + 4 * t4);
    *(float4*)&xs[d][4 * t4] = v;
  }
  #pragma unroll
  for (int i = 0; i < 2; ++i) enh[tid + 256 * i] = ensw[tid + 256 * i];
  const int t4 = tid & 15, m = tid >> 4;
  float bvv[4] = {-3.0e38f, -3.0e38f, -3.0e38f, -3.0e38f};
  int bii[4] = {0, 0, 0, 0};
  for (int kc = 0; kc < NK / 64; ++kc) {
    __syncthreads();
    #pragma unroll
    for (int i = 0; i < 8; ++i) {
      const int f = tid + 256 * i;
      const int kk = f & 63, dq = f >> 6;
      const float4 v = *(const float4*)(e + (size_t)(kc * 64 + kk) * ND + 4 * dq);
      esh[4 * dq + 0][kk] = v.x; esh[4 * dq + 1][kk] = v.y;
      esh[4 * dq + 2][kk] = v.z; esh[4 * dq + 3][kk] = v.w;
    }
    __syncthreads();
    float acc[4][4];
    #pragma unroll
    for (int a = 0; a < 4; ++a)
      #pragma unroll
      for (int cc = 0; cc < 4; ++cc) acc[a][cc] = 0.0f;
    #pragma unroll 8
    for (int d = 0; d < ND; ++d) {
      const float4 xv = *(const float4*)&xs[d][4 * t4];
      const float4 ev = *(const float4*)&esh[d][4 * m];
      const float xa[4] = {xv.x, xv.y, xv.z, xv.w};
      const float ea[4] = {ev.x, ev.y, ev.z, ev.w};
      #pragma unroll
      for (int a = 0; a < 4; ++a)
        #pragma unroll
        for (int cc = 0; cc < 4; ++cc) acc[a][cc] = fmaf(xa[a], ea[cc], acc[a][cc]);
    }
    const int kbase = kc * 64 + 4 * m;
    #pragma unroll
    for (int cc = 0; cc < 4; ++cc) {
      const float bias = 0.5f * enh[kbase + cc];
      const int kg = kbase + cc;
      #pragma unroll
      for (int a = 0; a < 4; ++a) {
        const float s = acc[a][cc] - bias;
        if (s > bvv[a] || (s == bvv[a] && kg < bii[a])) { bvv[a] = s; bii[a] = kg; }
      }
    }
  }
  #pragma unroll
  for (int a = 0; a < 4; ++a) { red_v[4 * t4 + a][m] = bvv[a]; red_i[4 * t4 + a][m] = bii[a]; }
  __syncthreads();
  if (tid < 64) {
    float v = red_v[tid][0]; int ix = red_i[tid][0];
    #pragma unroll
    for (int j = 1; j < 16; ++j) {
      const float vj = red_v[tid][j]; const int ij = red_i[tid][j];
      if (vj > v || (vj == v && ij < ix)) { v = vj; ix = ij; }
    }
    bidx[tid] = ix;
  }
  __syncthreads();
  const int t = tid & 63, dgg = tid >> 6;
  const float* er = e + (size_t)bidx[t] * ND;
  float* ob = out + ((size_t)b * ND) * NHW + hw0 + t;
  #pragma unroll
  for (int i = 0; i < 32; ++i) ob[(size_t)(dgg * 32 + i) * NHW] = er[dgg * 32 + i];
}

// --------------------------------------------------------------- launch -----
extern "C" void kernel_launch(void* const* d_in, const int* in_sizes, int n_in,
                              void* d_out, int out_size, void* d_ws, size_t ws_size,
                              hipStream_t stream) {
  const float* x = (const float*)d_in[0];
  const float* e = (const float*)d_in[1];
  float* out = (float*)d_out;
  char* ws = (char*)d_ws;

  f16* xhi = (f16*)(ws + WS_XHI);
  f16* xlo = (f16*)(ws + WS_XLO);
  f16* ehi = (f16*)(ws + WS_EHI);
  f16* elo = (f16*)(ws + WS_ELO);
  float* ens = (float*)(ws + WS_ENS);
  unsigned long long* win = (unsigned long long*)(ws + WS_WIN);

  if (ws_size >= WS_NEED_V4) {
    vq_prep3<<<1312, 256, 0, stream>>>(x, e, xhi, xlo, ehi, elo, ens, win);
    vq_score<<<1024, 512, 0, stream>>>(xhi, xlo, ehi, elo, ens, win);
    vq_scatter<<<512, 512, 0, stream>>>(win, e, out);
  } else if (ws_size >= WS_NEED_V3) {
    vq_prep2<<<1056, 256, 0, stream>>>(x, e, xhi, xlo, ehi, elo, ens);
    vq_mfma<<<256, 512, 0, stream>>>(xhi, xlo, ehi, elo, ens, e, out);
  } else {
    float* ensw = (float*)d_ws;
    vq_enorm<<<NK, 128, 0, stream>>>(e, ensw);
    vq_main_f32<<<16 * 64, 256, 0, stream>>>(x, e, ensw, out);
  }
}